// Round 1
// baseline (7688.816 us; speedup 1.0000x reference)
//
#include <hip/hip_runtime.h>

#define DEV __device__ __forceinline__

constexpr int T_SEQ = 1024;
constexpr int DMODEL = 512;
constexpr int NSYM = 1024;
constexpr int NPAT = 512;

// ---------------- epilogue modes ----------------
enum { E_BIAS = 0, E_GUMBEL = 1, E_POS = 2, E_RES = 3, E_GELU = 4, E_VQ = 5 };

// ---------------- generic fp32 GEMM ----------------
// C[M,N] = A[M,K] * op(B) + epilogue.  NNLAY=0: B is [N,K] (NT, dot of rows).
// NNLAY=1: B is [K,N].
template <int BM, int BN, int NNLAY, int EPI>
__global__ __launch_bounds__((BM / 64) * (BN / 64) * 64) void gemm_f32(
    const float* __restrict__ A, const float* __restrict__ Bm,
    const float* __restrict__ bias, const float* __restrict__ res,
    float* __restrict__ C, int M, int N, int K, int resMask,
    const int* __restrict__ ep, const int* __restrict__ tot) {
  constexpr int BK = 16;
  constexpr int WN = BN / 64;
  constexpr int NW = (BM / 64) * WN;
  constexpr int NT = NW * 64;
  __shared__ __align__(16) float As[BK][BM + 4];
  __shared__ __align__(16) float Bs[BK][BN + 4];
  const int tid = threadIdx.x;
  const int w = tid >> 6, lane = tid & 63;
  const int wy = w / WN, wx = w % WN;
  const int ly = lane >> 3, lx = lane & 7;
  const int bm = blockIdx.y * BM;
  const int bn = blockIdx.x * BN;

  float acc[8][8];
#pragma unroll
  for (int i = 0; i < 8; ++i)
#pragma unroll
    for (int j = 0; j < 8; ++j) acc[i][j] = 0.0f;

  for (int k0 = 0; k0 < K; k0 += BK) {
#pragma unroll
    for (int i = 0; i < (BM * BK / 4) / NT; ++i) {
      int idx = tid + i * NT;
      int r = idx >> 2, c4 = (idx & 3) << 2;
      const float4 v = *(const float4*)(A + (size_t)(bm + r) * K + k0 + c4);
      As[c4 + 0][r] = v.x;
      As[c4 + 1][r] = v.y;
      As[c4 + 2][r] = v.z;
      As[c4 + 3][r] = v.w;
    }
    if constexpr (NNLAY == 0) {
#pragma unroll
      for (int i = 0; i < (BN * BK / 4) / NT; ++i) {
        int idx = tid + i * NT;
        int r = idx >> 2, c4 = (idx & 3) << 2;
        const float4 v = *(const float4*)(Bm + (size_t)(bn + r) * K + k0 + c4);
        Bs[c4 + 0][r] = v.x;
        Bs[c4 + 1][r] = v.y;
        Bs[c4 + 2][r] = v.z;
        Bs[c4 + 3][r] = v.w;
      }
    } else {
#pragma unroll
      for (int i = 0; i < (BN * BK / 4) / NT; ++i) {
        int idx = tid + i * NT;
        int r = idx / (BN / 4), c4 = (idx % (BN / 4)) * 4;
        *(float4*)&Bs[r][c4] =
            *(const float4*)(Bm + (size_t)(k0 + r) * N + bn + c4);
      }
    }
    __syncthreads();
#pragma unroll
    for (int k = 0; k < BK; ++k) {
      float a[8], b[8];
      *(float4*)&a[0] = *(const float4*)&As[k][wy * 64 + ly * 8];
      *(float4*)&a[4] = *(const float4*)&As[k][wy * 64 + ly * 8 + 4];
      *(float4*)&b[0] = *(const float4*)&Bs[k][wx * 64 + lx * 8];
      *(float4*)&b[4] = *(const float4*)&Bs[k][wx * 64 + lx * 8 + 4];
#pragma unroll
      for (int i = 0; i < 8; ++i)
#pragma unroll
        for (int j = 0; j < 8; ++j) acc[i][j] = fmaf(a[i], b[j], acc[i][j]);
    }
    __syncthreads();
  }

  // ---- epilogue ----
  const int ncol = bn + wx * 64 + lx * 8;
  float bb[8];
  if constexpr (EPI == E_BIAS || EPI == E_RES || EPI == E_GELU) {
    *(float4*)&bb[0] = *(const float4*)(bias + ncol);
    *(float4*)&bb[4] = *(const float4*)(bias + ncol + 4);
  }
  float invt = 1.0f;
  if constexpr (EPI == E_VQ) {
    float t = 1.0f - 0.5f * (float)ep[0] / (float)tot[0];
    invt = 1.0f / fmaxf(0.5f, t);
  }
#pragma unroll
  for (int i = 0; i < 8; ++i) {
    const int m = bm + wy * 64 + ly * 8 + i;
    float o[8];
#pragma unroll
    for (int j = 0; j < 8; ++j) o[j] = acc[i][j];
    if constexpr (EPI == E_BIAS) {
#pragma unroll
      for (int j = 0; j < 8; ++j) o[j] += bb[j];
    } else if constexpr (EPI == E_GUMBEL) {
      float g[8];
      *(float4*)&g[0] = *(const float4*)(res + (size_t)m * N + ncol);
      *(float4*)&g[4] = *(const float4*)(res + (size_t)m * N + ncol + 4);
#pragma unroll
      for (int j = 0; j < 8; ++j) o[j] = 4.0f * o[j] + 2.0f * g[j];
    } else if constexpr (EPI == E_POS) {
      float g[8];
      const size_t pr = (size_t)(m & resMask) * N + ncol;
      *(float4*)&g[0] = *(const float4*)(res + pr);
      *(float4*)&g[4] = *(const float4*)(res + pr + 4);
#pragma unroll
      for (int j = 0; j < 8; ++j) o[j] += g[j];
    } else if constexpr (EPI == E_RES) {
      float g[8];
      *(float4*)&g[0] = *(const float4*)(res + (size_t)m * N + ncol);
      *(float4*)&g[4] = *(const float4*)(res + (size_t)m * N + ncol + 4);
#pragma unroll
      for (int j = 0; j < 8; ++j) o[j] += bb[j] + g[j];
    } else if constexpr (EPI == E_GELU) {
#pragma unroll
      for (int j = 0; j < 8; ++j) {
        float t = o[j] + bb[j];
        o[j] = 0.5f * t * (1.0f + erff(t * 0.7071067811865476f));
      }
    } else if constexpr (EPI == E_VQ) {
#pragma unroll
      for (int j = 0; j < 8; ++j) o[j] *= invt;
    }
    *(float4*)(C + (size_t)m * N + ncol) = *(float4*)&o[0];
    *(float4*)(C + (size_t)m * N + ncol + 4) = *(float4*)&o[4];
  }
}

// ---------------- flash attention (fp32, hd=64, T=1024, 8 heads) -------------
DEV int SW(int x) { return ((x ^ (x >> 3)) & 7) << 2; }

__global__ __launch_bounds__(64) void flash_attn(const float* __restrict__ qkv,
                                                 float* __restrict__ outp) {
  __shared__ __align__(16) float QT[64][64];
  __shared__ __align__(16) float KT[64][64];
  __shared__ __align__(16) float Vs[64][64];
  __shared__ __align__(16) float PT[64][64];
  const int lane = threadIdx.x;
  const int qt = blockIdx.x;  // 0..15
  const int bh = blockIdx.y;  // 0..63
  const int b = bh >> 3, hh = bh & 7;
  const int ly = lane >> 3, lx = lane & 7;
  const int rr = lane >> 4;          // 0..3
  const int cc = (lane & 15) << 2;   // 0,4,..,60

  const size_t baseQ = ((size_t)(b * T_SEQ + qt * 64)) * 1536 + hh * 64;
#pragma unroll
  for (int i = 0; i < 16; ++i) {
    int r = 4 * i + rr;
    float4 v = *(const float4*)(qkv + baseQ + (size_t)r * 1536 + cc);
    QT[cc + 0][r ^ SW(cc + 0)] = v.x;
    QT[cc + 1][r ^ SW(cc + 1)] = v.y;
    QT[cc + 2][r ^ SW(cc + 2)] = v.z;
    QT[cc + 3][r ^ SW(cc + 3)] = v.w;
  }

  float o[8][8] = {};
  float mrun[8], lrun[8];
#pragma unroll
  for (int i = 0; i < 8; ++i) {
    mrun[i] = -__builtin_huge_valf();
    lrun[i] = 0.0f;
  }

  for (int kt = 0; kt < 16; ++kt) {
    __syncthreads();
    const size_t baseK = ((size_t)(b * T_SEQ + kt * 64)) * 1536 + 512 + hh * 64;
    const size_t baseV = baseK + 512;
#pragma unroll
    for (int i = 0; i < 16; ++i) {
      int r = 4 * i + rr;
      float4 v = *(const float4*)(qkv + baseK + (size_t)r * 1536 + cc);
      KT[cc + 0][r ^ SW(cc + 0)] = v.x;
      KT[cc + 1][r ^ SW(cc + 1)] = v.y;
      KT[cc + 2][r ^ SW(cc + 2)] = v.z;
      KT[cc + 3][r ^ SW(cc + 3)] = v.w;
      float4 u = *(const float4*)(qkv + baseV + (size_t)r * 1536 + cc);
      *(float4*)&Vs[r][cc ^ SW(r)] = u;
    }
    __syncthreads();

    float s[8][8] = {};
#pragma unroll 4
    for (int d = 0; d < 64; ++d) {
      int sw = SW(d);
      float q[8], k[8];
      *(float4*)&q[0] = *(const float4*)&QT[d][(8 * ly) ^ sw];
      *(float4*)&q[4] = *(const float4*)&QT[d][(8 * ly + 4) ^ sw];
      *(float4*)&k[0] = *(const float4*)&KT[d][(8 * lx) ^ sw];
      *(float4*)&k[4] = *(const float4*)&KT[d][(8 * lx + 4) ^ sw];
#pragma unroll
      for (int i = 0; i < 8; ++i)
#pragma unroll
        for (int j = 0; j < 8; ++j) s[i][j] = fmaf(q[i], k[j], s[i][j]);
    }

#pragma unroll
    for (int i = 0; i < 8; ++i) {
#pragma unroll
      for (int j = 0; j < 8; ++j) s[i][j] *= 0.125f;
      float rm = s[i][0];
#pragma unroll
      for (int j = 1; j < 8; ++j) rm = fmaxf(rm, s[i][j]);
      rm = fmaxf(rm, __shfl_xor(rm, 1));
      rm = fmaxf(rm, __shfl_xor(rm, 2));
      rm = fmaxf(rm, __shfl_xor(rm, 4));
      float mnew = fmaxf(mrun[i], rm);
      float alpha = expf(mrun[i] - mnew);
      float rs = 0.0f;
#pragma unroll
      for (int j = 0; j < 8; ++j) {
        float p = expf(s[i][j] - mnew);
        s[i][j] = p;
        rs += p;
      }
      rs += __shfl_xor(rs, 1);
      rs += __shfl_xor(rs, 2);
      rs += __shfl_xor(rs, 4);
      lrun[i] = lrun[i] * alpha + rs;
      mrun[i] = mnew;
#pragma unroll
      for (int j = 0; j < 8; ++j) o[i][j] *= alpha;
    }

#pragma unroll
    for (int j = 0; j < 8; ++j) {
      int c = 8 * lx + j;
      int sw = SW(c);
      float4 v0 = make_float4(s[0][j], s[1][j], s[2][j], s[3][j]);
      float4 v1 = make_float4(s[4][j], s[5][j], s[6][j], s[7][j]);
      *(float4*)&PT[c][(8 * ly) ^ sw] = v0;
      *(float4*)&PT[c][(8 * ly + 4) ^ sw] = v1;
    }
    __syncthreads();

#pragma unroll 4
    for (int c = 0; c < 64; ++c) {
      int sw = SW(c);
      float p[8], vv[8];
      *(float4*)&p[0] = *(const float4*)&PT[c][(8 * ly) ^ sw];
      *(float4*)&p[4] = *(const float4*)&PT[c][(8 * ly + 4) ^ sw];
      *(float4*)&vv[0] = *(const float4*)&Vs[c][(8 * lx) ^ sw];
      *(float4*)&vv[4] = *(const float4*)&Vs[c][(8 * lx + 4) ^ sw];
#pragma unroll
      for (int i = 0; i < 8; ++i)
#pragma unroll
        for (int j = 0; j < 8; ++j) o[i][j] = fmaf(p[i], vv[j], o[i][j]);
    }
  }

  const size_t baseO = ((size_t)(b * T_SEQ + qt * 64)) * DMODEL + hh * 64;
#pragma unroll
  for (int i = 0; i < 8; ++i) {
    float inv = 1.0f / lrun[i];
    int r = 8 * ly + i;
    float4 w0 = make_float4(o[i][0] * inv, o[i][1] * inv, o[i][2] * inv,
                            o[i][3] * inv);
    float4 w1 = make_float4(o[i][4] * inv, o[i][5] * inv, o[i][6] * inv,
                            o[i][7] * inv);
    *(float4*)(outp + baseO + (size_t)r * DMODEL + 8 * lx) = w0;
    *(float4*)(outp + baseO + (size_t)r * DMODEL + 8 * lx + 4) = w1;
  }
}

// ---------------- row kernels (D=512, one wave per row, 4 rows/block) --------
DEV float wave_sum(float v) {
#pragma unroll
  for (int off = 1; off < 64; off <<= 1) v += __shfl_xor(v, off);
  return v;
}

template <int DOL2>
__global__ __launch_bounds__(256) void ln_kernel(const float* __restrict__ x,
                                                 const float* __restrict__ g,
                                                 const float* __restrict__ b,
                                                 float* __restrict__ y) {
  const int row = blockIdx.x * 4 + (threadIdx.x >> 6);
  const int lane = threadIdx.x & 63;
  const float* xr = x + (size_t)row * DMODEL;
  float v[8];
  *(float4*)&v[0] = *(const float4*)(xr + lane * 8);
  *(float4*)&v[4] = *(const float4*)(xr + lane * 8 + 4);
  float s = 0.0f;
#pragma unroll
  for (int j = 0; j < 8; ++j) s += v[j];
  s = wave_sum(s);
  float mean = s * (1.0f / 512.0f);
  float s2 = 0.0f;
#pragma unroll
  for (int j = 0; j < 8; ++j) {
    float d = v[j] - mean;
    s2 += d * d;
  }
  s2 = wave_sum(s2);
  float rstd = 1.0f / sqrtf(s2 * (1.0f / 512.0f) + 1e-5f);
  float gg[8], bv[8];
  *(float4*)&gg[0] = *(const float4*)(g + lane * 8);
  *(float4*)&gg[4] = *(const float4*)(g + lane * 8 + 4);
  *(float4*)&bv[0] = *(const float4*)(b + lane * 8);
  *(float4*)&bv[4] = *(const float4*)(b + lane * 8 + 4);
  float t[8];
#pragma unroll
  for (int j = 0; j < 8; ++j) t[j] = (v[j] - mean) * rstd * gg[j] + bv[j];
  if constexpr (DOL2) {
    float n2 = 0.0f;
#pragma unroll
    for (int j = 0; j < 8; ++j) n2 += t[j] * t[j];
    n2 = wave_sum(n2);
    float den = fmaxf(sqrtf(n2), 1e-12f);
#pragma unroll
    for (int j = 0; j < 8; ++j) t[j] /= den;
  }
  float* yr = y + (size_t)row * DMODEL;
  *(float4*)(yr + lane * 8) = *(float4*)&t[0];
  *(float4*)(yr + lane * 8 + 4) = *(float4*)&t[4];
}

__global__ __launch_bounds__(256) void l2_rows(const float* __restrict__ x,
                                               float* __restrict__ y) {
  const int row = blockIdx.x * 4 + (threadIdx.x >> 6);
  const int lane = threadIdx.x & 63;
  const float* xr = x + (size_t)row * DMODEL;
  float v[8];
  *(float4*)&v[0] = *(const float4*)(xr + lane * 8);
  *(float4*)&v[4] = *(const float4*)(xr + lane * 8 + 4);
  float n2 = 0.0f;
#pragma unroll
  for (int j = 0; j < 8; ++j) n2 += v[j] * v[j];
  n2 = wave_sum(n2);
  float den = fmaxf(sqrtf(n2), 1e-12f);
#pragma unroll
  for (int j = 0; j < 8; ++j) v[j] /= den;
  float* yr = y + (size_t)row * DMODEL;
  *(float4*)(yr + lane * 8) = *(float4*)&v[0];
  *(float4*)(yr + lane * 8 + 4) = *(float4*)&v[4];
}

// in-place softmax over rows of length 1024 (one block of 256 per row)
__global__ __launch_bounds__(256) void softmax_rows(float* __restrict__ p) {
  const int row = blockIdx.x;
  const int tid = threadIdx.x;
  float* pr = p + (size_t)row * NSYM;
  float4 v = *(const float4*)(pr + tid * 4);
  float m = fmaxf(fmaxf(v.x, v.y), fmaxf(v.z, v.w));
#pragma unroll
  for (int off = 1; off < 64; off <<= 1) m = fmaxf(m, __shfl_xor(m, off));
  __shared__ float red[4];
  const int wv = tid >> 6;
  if ((tid & 63) == 0) red[wv] = m;
  __syncthreads();
  m = fmaxf(fmaxf(red[0], red[1]), fmaxf(red[2], red[3]));
  float e0 = expf(v.x - m), e1 = expf(v.y - m), e2 = expf(v.z - m),
        e3 = expf(v.w - m);
  float s = e0 + e1 + e2 + e3;
#pragma unroll
  for (int off = 1; off < 64; off <<= 1) s += __shfl_xor(s, off);
  __syncthreads();
  if ((tid & 63) == 0) red[wv] = s;
  __syncthreads();
  s = red[0] + red[1] + red[2] + red[3];
  float4 w = make_float4(e0 / s, e1 / s, e2 / s, e3 / s);
  *(float4*)(pr + tid * 4) = w;
}

// argmax + one_hot + gather (one wave per row)
__global__ __launch_bounds__(256) void vq_finalize(
    const float* __restrict__ logits, const float* __restrict__ patterns,
    float* __restrict__ emb, float* __restrict__ assign,
    float* __restrict__ idxf) {
  const int row = blockIdx.x * 4 + (threadIdx.x >> 6);
  const int lane = threadIdx.x & 63;
  const float* lr = logits + (size_t)row * NPAT;
  float best = -__builtin_huge_valf();
  int bi = 0;
#pragma unroll
  for (int jj = 0; jj < 8; ++jj) {
    int j = lane + jj * 64;
    float v = lr[j];
    if (v > best) {
      best = v;
      bi = j;
    }
  }
#pragma unroll
  for (int off = 1; off < 64; off <<= 1) {
    float ob = __shfl_xor(best, off);
    int oi = __shfl_xor(bi, off);
    if (ob > best || (ob == best && oi < bi)) {
      best = ob;
      bi = oi;
    }
  }
  const float* pr = patterns + (size_t)bi * DMODEL;
#pragma unroll
  for (int g = 0; g < 2; ++g) {
    int c = lane * 8 + g * 4;
    float4 pv = *(const float4*)(pr + c);
    *(float4*)(emb + (size_t)row * DMODEL + c) = pv;
    float4 av;
    av.x = (c + 0 == bi) ? 1.0f : 0.0f;
    av.y = (c + 1 == bi) ? 1.0f : 0.0f;
    av.z = (c + 2 == bi) ? 1.0f : 0.0f;
    av.w = (c + 3 == bi) ? 1.0f : 0.0f;
    *(float4*)(assign + (size_t)row * NPAT + c) = av;
  }
  if (lane == 0) idxf[row] = (float)bi;
}

// ---------------- host launch ----------------
extern "C" void kernel_launch(void* const* d_in, const int* in_sizes, int n_in,
                              void* d_out, int out_size, void* d_ws,
                              size_t ws_size, hipStream_t stream) {
  (void)in_sizes;
  (void)n_in;
  (void)out_size;
  (void)ws_size;
  const float* x = (const float*)d_in[0];
  const float* gumbel = (const float*)d_in[1];
  const float* sym_w = (const float*)d_in[2];
  const float* sym_b = (const float*)d_in[3];
  const float* codebook = (const float*)d_in[4];
  const float* pos_enc = (const float*)d_in[5];
  const float* attn_in_w = (const float*)d_in[6];
  const float* attn_in_b = (const float*)d_in[7];
  const float* attn_out_w = (const float*)d_in[8];
  const float* attn_out_b = (const float*)d_in[9];
  const float* n1_g = (const float*)d_in[10];
  const float* n1_b = (const float*)d_in[11];
  const float* n2_g = (const float*)d_in[12];
  const float* n2_b = (const float*)d_in[13];
  const float* ffn_w1 = (const float*)d_in[14];
  const float* ffn_b1 = (const float*)d_in[15];
  const float* ffn_w2 = (const float*)d_in[16];
  const float* ffn_b2 = (const float*)d_in[17];
  const float* q_w = (const float*)d_in[18];
  const float* q_b = (const float*)d_in[19];
  const float* qln_g = (const float*)d_in[20];
  const float* qln_b = (const float*)d_in[21];
  const float* patterns = (const float*)d_in[22];
  const int* epoch = (const int*)d_in[23];
  const int* tot = (const int*)d_in[24];

  float* out = (float*)d_out;
  float* emb = out;                    // [8192,512]
  float* assign = out + 4194304;       // [8192,512]
  float* logits = out + 8388608;       // [8192,512]
  float* h = out + 12582912;           // [8192,512]
  float* idxf = out + 16777216;        // [8192]

  float* ws = (float*)d_ws;
  float* r1 = ws;                      // 16777216 floats: soft/qkv/mid
  float* hn = ws + 16777216;           // 4194304
  float* r3 = ws + 20971520;           // 4194304: hp/attno/q
  float* cbn = ws + 25165824;          // 524288
  float* patn = ws + 25690112;         // 262144

  // 1. hp = x @ sym_w^T + sym_b   [8192,512] K=1024
  gemm_f32<64, 128, 0, E_BIAS><<<dim3(4, 128), 128, 0, stream>>>(
      x, sym_w, sym_b, nullptr, r3, 8192, 512, 1024, 0, nullptr, nullptr);
  // 2. cbn = l2norm(codebook)  [1024,512]
  l2_rows<<<256, 256, 0, stream>>>(codebook, cbn);
  // 3. hp <- l2norm(hp) in place
  l2_rows<<<2048, 256, 0, stream>>>(r3, r3);
  // 4. soft_pre = 4*(hp_n@cbn^T) + 2*gumbel   [8192,1024] K=512
  gemm_f32<128, 128, 0, E_GUMBEL><<<dim3(8, 64), 256, 0, stream>>>(
      r3, cbn, nullptr, gumbel, r1, 8192, 1024, 512, 0, nullptr, nullptr);
  // 5. softmax rows
  softmax_rows<<<8192, 256, 0, stream>>>(r1);
  // 6. h = soft @ codebook + pos_enc   [8192,512] K=1024 (NN)
  gemm_f32<64, 128, 1, E_POS><<<dim3(4, 128), 128, 0, stream>>>(
      r1, codebook, nullptr, pos_enc, h, 8192, 512, 1024, 1023, nullptr,
      nullptr);

  for (int l = 0; l < 4; ++l) {
    const float* inw = attn_in_w + (size_t)l * 1536 * 512;
    const float* inb = attn_in_b + (size_t)l * 1536;
    const float* outw = attn_out_w + (size_t)l * 512 * 512;
    const float* outb = attn_out_b + (size_t)l * 512;
    const float* w1 = ffn_w1 + (size_t)l * 2048 * 512;
    const float* b1 = ffn_b1 + (size_t)l * 2048;
    const float* w2 = ffn_w2 + (size_t)l * 512 * 2048;
    const float* b2 = ffn_b2 + (size_t)l * 512;

    ln_kernel<0><<<2048, 256, 0, stream>>>(h, n1_g + l * 512, n1_b + l * 512,
                                           hn);
    gemm_f32<128, 128, 0, E_BIAS><<<dim3(12, 64), 256, 0, stream>>>(
        hn, inw, inb, nullptr, r1, 8192, 1536, 512, 0, nullptr, nullptr);
    flash_attn<<<dim3(16, 64), 64, 0, stream>>>(r1, r3);
    gemm_f32<64, 128, 0, E_RES><<<dim3(4, 128), 128, 0, stream>>>(
        r3, outw, outb, h, h, 8192, 512, 512, 0, nullptr, nullptr);
    ln_kernel<0><<<2048, 256, 0, stream>>>(h, n2_g + l * 512, n2_b + l * 512,
                                           hn);
    gemm_f32<128, 128, 0, E_GELU><<<dim3(16, 64), 256, 0, stream>>>(
        hn, w1, b1, nullptr, r1, 8192, 2048, 512, 0, nullptr, nullptr);
    gemm_f32<64, 128, 0, E_RES><<<dim3(4, 128), 128, 0, stream>>>(
        r1, w2, b2, h, h, 8192, 512, 2048, 0, nullptr, nullptr);
  }

  // VQ head
  gemm_f32<64, 128, 0, E_BIAS><<<dim3(4, 128), 128, 0, stream>>>(
      h, q_w, q_b, nullptr, r3, 8192, 512, 512, 0, nullptr, nullptr);
  ln_kernel<1><<<2048, 256, 0, stream>>>(r3, qln_g, qln_b, r3);
  l2_rows<<<128, 256, 0, stream>>>(patterns, patn);
  gemm_f32<64, 128, 0, E_VQ><<<dim3(4, 128), 128, 0, stream>>>(
      r3, patn, nullptr, nullptr, logits, 8192, 512, 512, 0, epoch, tot);
  vq_finalize<<<2048, 256, 0, stream>>>(logits, patterns, emb, assign, idxf);
}

// Round 2
// 5230.587 us; speedup vs baseline: 1.4700x; 1.4700x over previous
//
#include <hip/hip_runtime.h>

#define DEV __device__ __forceinline__

constexpr int T_SEQ = 1024;
constexpr int DMODEL = 512;
constexpr int NSYM = 1024;
constexpr int NPAT = 512;

// ---------------- epilogue modes ----------------
enum { E_BIAS = 0, E_GUMBEL = 1, E_POS = 2, E_RES = 3, E_GELU = 4, E_VQ = 5 };

// ---------------- generic fp32 GEMM ----------------
// C[M,N] = A[M,K] * op(B) + epilogue.  NNLAY=0: B is [N,K] (NT, dot of rows).
// NNLAY=1: B is [K,N].
template <int BM, int BN, int NNLAY, int EPI>
__global__ __launch_bounds__((BM / 64) * (BN / 64) * 64) void gemm_f32(
    const float* __restrict__ A, const float* __restrict__ Bm,
    const float* __restrict__ bias, const float* __restrict__ res,
    float* __restrict__ C, int M, int N, int K, int resMask,
    const int* __restrict__ ep, const int* __restrict__ tot) {
  constexpr int BK = 16;
  constexpr int WN = BN / 64;
  constexpr int NW = (BM / 64) * WN;
  constexpr int NT = NW * 64;
  __shared__ __align__(16) float As[BK][BM + 4];
  __shared__ __align__(16) float Bs[BK][BN + 4];
  const int tid = threadIdx.x;
  const int w = tid >> 6, lane = tid & 63;
  const int wy = w / WN, wx = w % WN;
  const int ly = lane >> 3, lx = lane & 7;
  const int bm = blockIdx.y * BM;
  const int bn = blockIdx.x * BN;

  float acc[8][8];
#pragma unroll
  for (int i = 0; i < 8; ++i)
#pragma unroll
    for (int j = 0; j < 8; ++j) acc[i][j] = 0.0f;

  for (int k0 = 0; k0 < K; k0 += BK) {
#pragma unroll
    for (int i = 0; i < (BM * BK / 4) / NT; ++i) {
      int idx = tid + i * NT;
      int r = idx >> 2, c4 = (idx & 3) << 2;
      const float4 v = *(const float4*)(A + (size_t)(bm + r) * K + k0 + c4);
      As[c4 + 0][r] = v.x;
      As[c4 + 1][r] = v.y;
      As[c4 + 2][r] = v.z;
      As[c4 + 3][r] = v.w;
    }
    if constexpr (NNLAY == 0) {
#pragma unroll
      for (int i = 0; i < (BN * BK / 4) / NT; ++i) {
        int idx = tid + i * NT;
        int r = idx >> 2, c4 = (idx & 3) << 2;
        const float4 v = *(const float4*)(Bm + (size_t)(bn + r) * K + k0 + c4);
        Bs[c4 + 0][r] = v.x;
        Bs[c4 + 1][r] = v.y;
        Bs[c4 + 2][r] = v.z;
        Bs[c4 + 3][r] = v.w;
      }
    } else {
#pragma unroll
      for (int i = 0; i < (BN * BK / 4) / NT; ++i) {
        int idx = tid + i * NT;
        int r = idx / (BN / 4), c4 = (idx % (BN / 4)) * 4;
        *(float4*)&Bs[r][c4] =
            *(const float4*)(Bm + (size_t)(k0 + r) * N + bn + c4);
      }
    }
    __syncthreads();
#pragma unroll
    for (int k = 0; k < BK; ++k) {
      float a[8], b[8];
      *(float4*)&a[0] = *(const float4*)&As[k][wy * 64 + ly * 8];
      *(float4*)&a[4] = *(const float4*)&As[k][wy * 64 + ly * 8 + 4];
      *(float4*)&b[0] = *(const float4*)&Bs[k][wx * 64 + lx * 8];
      *(float4*)&b[4] = *(const float4*)&Bs[k][wx * 64 + lx * 8 + 4];
#pragma unroll
      for (int i = 0; i < 8; ++i)
#pragma unroll
        for (int j = 0; j < 8; ++j) acc[i][j] = fmaf(a[i], b[j], acc[i][j]);
    }
    __syncthreads();
  }

  // ---- epilogue ----
  const int ncol = bn + wx * 64 + lx * 8;
  float bb[8];
  if constexpr (EPI == E_BIAS || EPI == E_RES || EPI == E_GELU) {
    *(float4*)&bb[0] = *(const float4*)(bias + ncol);
    *(float4*)&bb[4] = *(const float4*)(bias + ncol + 4);
  }
  float invt = 1.0f;
  if constexpr (EPI == E_VQ) {
    float t = 1.0f - 0.5f * (float)ep[0] / (float)tot[0];
    invt = 1.0f / fmaxf(0.5f, t);
  }
#pragma unroll
  for (int i = 0; i < 8; ++i) {
    const int m = bm + wy * 64 + ly * 8 + i;
    float o[8];
#pragma unroll
    for (int j = 0; j < 8; ++j) o[j] = acc[i][j];
    if constexpr (EPI == E_BIAS) {
#pragma unroll
      for (int j = 0; j < 8; ++j) o[j] += bb[j];
    } else if constexpr (EPI == E_GUMBEL) {
      float g[8];
      *(float4*)&g[0] = *(const float4*)(res + (size_t)m * N + ncol);
      *(float4*)&g[4] = *(const float4*)(res + (size_t)m * N + ncol + 4);
#pragma unroll
      for (int j = 0; j < 8; ++j) o[j] = 4.0f * o[j] + 2.0f * g[j];
    } else if constexpr (EPI == E_POS) {
      float g[8];
      const size_t pr = (size_t)(m & resMask) * N + ncol;
      *(float4*)&g[0] = *(const float4*)(res + pr);
      *(float4*)&g[4] = *(const float4*)(res + pr + 4);
#pragma unroll
      for (int j = 0; j < 8; ++j) o[j] += g[j];
    } else if constexpr (EPI == E_RES) {
      float g[8];
      *(float4*)&g[0] = *(const float4*)(res + (size_t)m * N + ncol);
      *(float4*)&g[4] = *(const float4*)(res + (size_t)m * N + ncol + 4);
#pragma unroll
      for (int j = 0; j < 8; ++j) o[j] += bb[j] + g[j];
    } else if constexpr (EPI == E_GELU) {
#pragma unroll
      for (int j = 0; j < 8; ++j) {
        float t = o[j] + bb[j];
        o[j] = 0.5f * t * (1.0f + erff(t * 0.7071067811865476f));
      }
    } else if constexpr (EPI == E_VQ) {
#pragma unroll
      for (int j = 0; j < 8; ++j) o[j] *= invt;
    }
    *(float4*)(C + (size_t)m * N + ncol) = *(float4*)&o[0];
    *(float4*)(C + (size_t)m * N + ncol + 4) = *(float4*)&o[4];
  }
}

// ---------------- flash attention v2 -----------------------------------------
// 4 waves/block, each wave owns 32 q-rows; K/V 64x64 tiles shared in LDS.
// LDS = 32K (QT) + 16K (KT) + 16K (Vs) = 64KB -> 2 blocks/CU -> 2 waves/SIMD.
// PV uses register broadcasts (__shfl) instead of an LDS transpose buffer.
DEV int SW(int x) { return ((x ^ (x >> 3)) & 7) << 2; }

__global__ __launch_bounds__(256) void flash_attn2(
    const float* __restrict__ qkv, float* __restrict__ outp) {
  __shared__ __align__(16) float QT[4][64][32];  // [wave][d][q ^ SW(d)]
  __shared__ __align__(16) float KT[64][64];     // [d][k ^ SW(d)]
  __shared__ __align__(16) float Vs[64][64];     // [kv][d ^ SW(kv)]
  const int tid = threadIdx.x;
  const int w = tid >> 6, lane = tid & 63;
  const int ly = lane >> 3, lx = lane & 7;
  const int qt = blockIdx.x;  // 0..7 (128 q-rows per block)
  const int bh = blockIdx.y;  // 0..63
  const int b = bh >> 3, hh = bh & 7;

  // ---- load this wave's 32-row Q tile (transposed + swizzled) ----
  const int qbase = qt * 128 + w * 32;
  const int lr = lane >> 4;          // 0..3
  const int lc = (lane & 15) << 2;   // 0,4,..,60
  const size_t baseQ = ((size_t)(b * T_SEQ + qbase)) * 1536 + hh * 64;
#pragma unroll
  for (int i = 0; i < 8; ++i) {
    int r = lr + 4 * i;  // 0..31
    float4 v = *(const float4*)(qkv + baseQ + (size_t)r * 1536 + lc);
    QT[w][lc + 0][r ^ SW(lc + 0)] = v.x;
    QT[w][lc + 1][r ^ SW(lc + 1)] = v.y;
    QT[w][lc + 2][r ^ SW(lc + 2)] = v.z;
    QT[w][lc + 3][r ^ SW(lc + 3)] = v.w;
  }

  float o[4][8] = {};
  float mrun[4], lrun[4];
#pragma unroll
  for (int i = 0; i < 4; ++i) {
    mrun[i] = -__builtin_huge_valf();
    lrun[i] = 0.0f;
  }

  const int kr = tid >> 4;          // 0..15 (block-wide K/V load row)
  const int kc = (tid & 15) << 2;   // 0,4,..,60

  for (int kt = 0; kt < 16; ++kt) {
    __syncthreads();  // previous PV finished reading Vs
    const size_t baseK =
        ((size_t)(b * T_SEQ + kt * 64)) * 1536 + 512 + hh * 64;
#pragma unroll
    for (int jj = 0; jj < 4; ++jj) {
      int r = kr + 16 * jj;  // 0..63
      float4 kv4 = *(const float4*)(qkv + baseK + (size_t)r * 1536 + kc);
      KT[kc + 0][r ^ SW(kc + 0)] = kv4.x;
      KT[kc + 1][r ^ SW(kc + 1)] = kv4.y;
      KT[kc + 2][r ^ SW(kc + 2)] = kv4.z;
      KT[kc + 3][r ^ SW(kc + 3)] = kv4.w;
      float4 vv4 = *(const float4*)(qkv + baseK + 512 + (size_t)r * 1536 + kc);
      *(float4*)&Vs[r][kc ^ SW(r)] = vv4;
    }
    __syncthreads();

    // ---- S = Q K^T (32x64 per wave), micro-tile 4x8 per lane ----
    float s[4][8] = {};
#pragma unroll 4
    for (int d = 0; d < 64; ++d) {
      int sw = SW(d);
      float q[4], k[8];
      *(float4*)&q[0] = *(const float4*)&QT[w][d][(4 * ly) ^ sw];
      *(float4*)&k[0] = *(const float4*)&KT[d][(8 * lx) ^ sw];
      *(float4*)&k[4] = *(const float4*)&KT[d][(8 * lx + 4) ^ sw];
#pragma unroll
      for (int i = 0; i < 4; ++i)
#pragma unroll
        for (int j = 0; j < 8; ++j) s[i][j] = fmaf(q[i], k[j], s[i][j]);
    }

    // ---- online softmax (rows 4*ly+i, spread across lx lanes) ----
#pragma unroll
    for (int i = 0; i < 4; ++i) {
#pragma unroll
      for (int j = 0; j < 8; ++j) s[i][j] *= 0.125f;
      float rm = s[i][0];
#pragma unroll
      for (int j = 1; j < 8; ++j) rm = fmaxf(rm, s[i][j]);
      rm = fmaxf(rm, __shfl_xor(rm, 1));
      rm = fmaxf(rm, __shfl_xor(rm, 2));
      rm = fmaxf(rm, __shfl_xor(rm, 4));
      float mnew = fmaxf(mrun[i], rm);
      float alpha = expf(mrun[i] - mnew);
      float rs = 0.0f;
#pragma unroll
      for (int j = 0; j < 8; ++j) {
        float p = expf(s[i][j] - mnew);
        s[i][j] = p;
        rs += p;
      }
      rs += __shfl_xor(rs, 1);
      rs += __shfl_xor(rs, 2);
      rs += __shfl_xor(rs, 4);
      lrun[i] = lrun[i] * alpha + rs;
      mrun[i] = mnew;
#pragma unroll
      for (int j = 0; j < 8; ++j) o[i][j] *= alpha;
    }

    // ---- O += P V via register broadcast (no LDS transpose) ----
#pragma unroll 4
    for (int c = 0; c < 64; ++c) {
      const int srcl = (ly << 3) | (c >> 3);
      float pb[4];
      pb[0] = __shfl(s[0][c & 7], srcl);
      pb[1] = __shfl(s[1][c & 7], srcl);
      pb[2] = __shfl(s[2][c & 7], srcl);
      pb[3] = __shfl(s[3][c & 7], srcl);
      int sw = SW(c);
      float vv[8];
      *(float4*)&vv[0] = *(const float4*)&Vs[c][(8 * lx) ^ sw];
      *(float4*)&vv[4] = *(const float4*)&Vs[c][(8 * lx + 4) ^ sw];
#pragma unroll
      for (int i = 0; i < 4; ++i)
#pragma unroll
        for (int j = 0; j < 8; ++j) o[i][j] = fmaf(pb[i], vv[j], o[i][j]);
    }
  }

  // ---- epilogue: normalize and store ----
  const size_t baseO = ((size_t)(b * T_SEQ + qbase)) * DMODEL + hh * 64;
#pragma unroll
  for (int i = 0; i < 4; ++i) {
    float inv = 1.0f / lrun[i];
    int r = 4 * ly + i;
    float4 w0 = make_float4(o[i][0] * inv, o[i][1] * inv, o[i][2] * inv,
                            o[i][3] * inv);
    float4 w1 = make_float4(o[i][4] * inv, o[i][5] * inv, o[i][6] * inv,
                            o[i][7] * inv);
    *(float4*)(outp + baseO + (size_t)r * DMODEL + 8 * lx) = w0;
    *(float4*)(outp + baseO + (size_t)r * DMODEL + 8 * lx + 4) = w1;
  }
}

// ---------------- row kernels (D=512, one wave per row, 4 rows/block) --------
DEV float wave_sum(float v) {
#pragma unroll
  for (int off = 1; off < 64; off <<= 1) v += __shfl_xor(v, off);
  return v;
}

template <int DOL2>
__global__ __launch_bounds__(256) void ln_kernel(const float* __restrict__ x,
                                                 const float* __restrict__ g,
                                                 const float* __restrict__ b,
                                                 float* __restrict__ y) {
  const int row = blockIdx.x * 4 + (threadIdx.x >> 6);
  const int lane = threadIdx.x & 63;
  const float* xr = x + (size_t)row * DMODEL;
  float v[8];
  *(float4*)&v[0] = *(const float4*)(xr + lane * 8);
  *(float4*)&v[4] = *(const float4*)(xr + lane * 8 + 4);
  float s = 0.0f;
#pragma unroll
  for (int j = 0; j < 8; ++j) s += v[j];
  s = wave_sum(s);
  float mean = s * (1.0f / 512.0f);
  float s2 = 0.0f;
#pragma unroll
  for (int j = 0; j < 8; ++j) {
    float d = v[j] - mean;
    s2 += d * d;
  }
  s2 = wave_sum(s2);
  float rstd = 1.0f / sqrtf(s2 * (1.0f / 512.0f) + 1e-5f);
  float gg[8], bv[8];
  *(float4*)&gg[0] = *(const float4*)(g + lane * 8);
  *(float4*)&gg[4] = *(const float4*)(g + lane * 8 + 4);
  *(float4*)&bv[0] = *(const float4*)(b + lane * 8);
  *(float4*)&bv[4] = *(const float4*)(b + lane * 8 + 4);
  float t[8];
#pragma unroll
  for (int j = 0; j < 8; ++j) t[j] = (v[j] - mean) * rstd * gg[j] + bv[j];
  if constexpr (DOL2) {
    float n2 = 0.0f;
#pragma unroll
    for (int j = 0; j < 8; ++j) n2 += t[j] * t[j];
    n2 = wave_sum(n2);
    float den = fmaxf(sqrtf(n2), 1e-12f);
#pragma unroll
    for (int j = 0; j < 8; ++j) t[j] /= den;
  }
  float* yr = y + (size_t)row * DMODEL;
  *(float4*)(yr + lane * 8) = *(float4*)&t[0];
  *(float4*)(yr + lane * 8 + 4) = *(float4*)&t[4];
}

__global__ __launch_bounds__(256) void l2_rows(const float* __restrict__ x,
                                               float* __restrict__ y) {
  const int row = blockIdx.x * 4 + (threadIdx.x >> 6);
  const int lane = threadIdx.x & 63;
  const float* xr = x + (size_t)row * DMODEL;
  float v[8];
  *(float4*)&v[0] = *(const float4*)(xr + lane * 8);
  *(float4*)&v[4] = *(const float4*)(xr + lane * 8 + 4);
  float n2 = 0.0f;
#pragma unroll
  for (int j = 0; j < 8; ++j) n2 += v[j] * v[j];
  n2 = wave_sum(n2);
  float den = fmaxf(sqrtf(n2), 1e-12f);
#pragma unroll
  for (int j = 0; j < 8; ++j) v[j] /= den;
  float* yr = y + (size_t)row * DMODEL;
  *(float4*)(yr + lane * 8) = *(float4*)&v[0];
  *(float4*)(yr + lane * 8 + 4) = *(float4*)&v[4];
}

// in-place softmax over rows of length 1024 (one block of 256 per row)
__global__ __launch_bounds__(256) void softmax_rows(float* __restrict__ p) {
  const int row = blockIdx.x;
  const int tid = threadIdx.x;
  float* pr = p + (size_t)row * NSYM;
  float4 v = *(const float4*)(pr + tid * 4);
  float m = fmaxf(fmaxf(v.x, v.y), fmaxf(v.z, v.w));
#pragma unroll
  for (int off = 1; off < 64; off <<= 1) m = fmaxf(m, __shfl_xor(m, off));
  __shared__ float red[4];
  const int wv = tid >> 6;
  if ((tid & 63) == 0) red[wv] = m;
  __syncthreads();
  m = fmaxf(fmaxf(red[0], red[1]), fmaxf(red[2], red[3]));
  float e0 = expf(v.x - m), e1 = expf(v.y - m), e2 = expf(v.z - m),
        e3 = expf(v.w - m);
  float s = e0 + e1 + e2 + e3;
#pragma unroll
  for (int off = 1; off < 64; off <<= 1) s += __shfl_xor(s, off);
  __syncthreads();
  if ((tid & 63) == 0) red[wv] = s;
  __syncthreads();
  s = red[0] + red[1] + red[2] + red[3];
  float4 w = make_float4(e0 / s, e1 / s, e2 / s, e3 / s);
  *(float4*)(pr + tid * 4) = w;
}

// argmax + one_hot + gather (one wave per row)
__global__ __launch_bounds__(256) void vq_finalize(
    const float* __restrict__ logits, const float* __restrict__ patterns,
    float* __restrict__ emb, float* __restrict__ assign,
    float* __restrict__ idxf) {
  const int row = blockIdx.x * 4 + (threadIdx.x >> 6);
  const int lane = threadIdx.x & 63;
  const float* lr = logits + (size_t)row * NPAT;
  float best = -__builtin_huge_valf();
  int bi = 0;
#pragma unroll
  for (int jj = 0; jj < 8; ++jj) {
    int j = lane + jj * 64;
    float v = lr[j];
    if (v > best) {
      best = v;
      bi = j;
    }
  }
#pragma unroll
  for (int off = 1; off < 64; off <<= 1) {
    float ob = __shfl_xor(best, off);
    int oi = __shfl_xor(bi, off);
    if (ob > best || (ob == best && oi < bi)) {
      best = ob;
      bi = oi;
    }
  }
  const float* pr = patterns + (size_t)bi * DMODEL;
#pragma unroll
  for (int g = 0; g < 2; ++g) {
    int c = lane * 8 + g * 4;
    float4 pv = *(const float4*)(pr + c);
    *(float4*)(emb + (size_t)row * DMODEL + c) = pv;
    float4 av;
    av.x = (c + 0 == bi) ? 1.0f : 0.0f;
    av.y = (c + 1 == bi) ? 1.0f : 0.0f;
    av.z = (c + 2 == bi) ? 1.0f : 0.0f;
    av.w = (c + 3 == bi) ? 1.0f : 0.0f;
    *(float4*)(assign + (size_t)row * NPAT + c) = av;
  }
  if (lane == 0) idxf[row] = (float)bi;
}

// ---------------- host launch ----------------
extern "C" void kernel_launch(void* const* d_in, const int* in_sizes, int n_in,
                              void* d_out, int out_size, void* d_ws,
                              size_t ws_size, hipStream_t stream) {
  (void)in_sizes;
  (void)n_in;
  (void)out_size;
  (void)ws_size;
  const float* x = (const float*)d_in[0];
  const float* gumbel = (const float*)d_in[1];
  const float* sym_w = (const float*)d_in[2];
  const float* sym_b = (const float*)d_in[3];
  const float* codebook = (const float*)d_in[4];
  const float* pos_enc = (const float*)d_in[5];
  const float* attn_in_w = (const float*)d_in[6];
  const float* attn_in_b = (const float*)d_in[7];
  const float* attn_out_w = (const float*)d_in[8];
  const float* attn_out_b = (const float*)d_in[9];
  const float* n1_g = (const float*)d_in[10];
  const float* n1_b = (const float*)d_in[11];
  const float* n2_g = (const float*)d_in[12];
  const float* n2_b = (const float*)d_in[13];
  const float* ffn_w1 = (const float*)d_in[14];
  const float* ffn_b1 = (const float*)d_in[15];
  const float* ffn_w2 = (const float*)d_in[16];
  const float* ffn_b2 = (const float*)d_in[17];
  const float* q_w = (const float*)d_in[18];
  const float* q_b = (const float*)d_in[19];
  const float* qln_g = (const float*)d_in[20];
  const float* qln_b = (const float*)d_in[21];
  const float* patterns = (const float*)d_in[22];
  const int* epoch = (const int*)d_in[23];
  const int* tot = (const int*)d_in[24];

  float* out = (float*)d_out;
  float* emb = out;                    // [8192,512]
  float* assign = out + 4194304;       // [8192,512]
  float* logits = out + 8388608;       // [8192,512]
  float* h = out + 12582912;           // [8192,512]
  float* idxf = out + 16777216;        // [8192]

  float* ws = (float*)d_ws;
  float* r1 = ws;                      // 16777216 floats: soft/qkv/mid
  float* hn = ws + 16777216;           // 4194304
  float* r3 = ws + 20971520;           // 4194304: hp/attno/q
  float* cbn = ws + 25165824;          // 524288
  float* patn = ws + 25690112;         // 262144

  // 1. hp = x @ sym_w^T + sym_b   [8192,512] K=1024
  gemm_f32<64, 128, 0, E_BIAS><<<dim3(4, 128), 128, 0, stream>>>(
      x, sym_w, sym_b, nullptr, r3, 8192, 512, 1024, 0, nullptr, nullptr);
  // 2. cbn = l2norm(codebook)  [1024,512]
  l2_rows<<<256, 256, 0, stream>>>(codebook, cbn);
  // 3. hp <- l2norm(hp) in place
  l2_rows<<<2048, 256, 0, stream>>>(r3, r3);
  // 4. soft_pre = 4*(hp_n@cbn^T) + 2*gumbel   [8192,1024] K=512
  gemm_f32<128, 128, 0, E_GUMBEL><<<dim3(8, 64), 256, 0, stream>>>(
      r3, cbn, nullptr, gumbel, r1, 8192, 1024, 512, 0, nullptr, nullptr);
  // 5. softmax rows
  softmax_rows<<<8192, 256, 0, stream>>>(r1);
  // 6. h = soft @ codebook + pos_enc   [8192,512] K=1024 (NN)
  gemm_f32<64, 128, 1, E_POS><<<dim3(4, 128), 128, 0, stream>>>(
      r1, codebook, nullptr, pos_enc, h, 8192, 512, 1024, 1023, nullptr,
      nullptr);

  for (int l = 0; l < 4; ++l) {
    const float* inw = attn_in_w + (size_t)l * 1536 * 512;
    const float* inb = attn_in_b + (size_t)l * 1536;
    const float* outw = attn_out_w + (size_t)l * 512 * 512;
    const float* outb = attn_out_b + (size_t)l * 512;
    const float* w1 = ffn_w1 + (size_t)l * 2048 * 512;
    const float* b1 = ffn_b1 + (size_t)l * 2048;
    const float* w2 = ffn_w2 + (size_t)l * 512 * 2048;
    const float* b2 = ffn_b2 + (size_t)l * 512;

    ln_kernel<0><<<2048, 256, 0, stream>>>(h, n1_g + l * 512, n1_b + l * 512,
                                           hn);
    gemm_f32<128, 128, 0, E_BIAS><<<dim3(12, 64), 256, 0, stream>>>(
        hn, inw, inb, nullptr, r1, 8192, 1536, 512, 0, nullptr, nullptr);
    flash_attn2<<<dim3(8, 64), 256, 0, stream>>>(r1, r3);
    gemm_f32<64, 128, 0, E_RES><<<dim3(4, 128), 128, 0, stream>>>(
        r3, outw, outb, h, h, 8192, 512, 512, 0, nullptr, nullptr);
    ln_kernel<0><<<2048, 256, 0, stream>>>(h, n2_g + l * 512, n2_b + l * 512,
                                           hn);
    gemm_f32<128, 128, 0, E_GELU><<<dim3(16, 64), 256, 0, stream>>>(
        hn, w1, b1, nullptr, r1, 8192, 2048, 512, 0, nullptr, nullptr);
    gemm_f32<64, 128, 0, E_RES><<<dim3(4, 128), 128, 0, stream>>>(
        r1, w2, b2, h, h, 8192, 512, 2048, 0, nullptr, nullptr);
  }

  // VQ head
  gemm_f32<64, 128, 0, E_BIAS><<<dim3(4, 128), 128, 0, stream>>>(
      h, q_w, q_b, nullptr, r3, 8192, 512, 512, 0, nullptr, nullptr);
  ln_kernel<1><<<2048, 256, 0, stream>>>(r3, qln_g, qln_b, r3);
  l2_rows<<<128, 256, 0, stream>>>(patterns, patn);
  gemm_f32<64, 128, 0, E_VQ><<<dim3(4, 128), 128, 0, stream>>>(
      r3, patn, nullptr, nullptr, logits, 8192, 512, 512, 0, epoch, tot);
  vq_finalize<<<2048, 256, 0, stream>>>(logits, patterns, emb, assign, idxf);
}